// Round 16
// baseline (107.429 us; speedup 1.0000x reference)
//
#include <hip/hip_runtime.h>
#include <hip/hip_bf16.h>

// MultiHeadAttentionRoPE: B=2,S=2048,D=1024,H=16,Dh=64 causal, fp32 in/out,
// bf16 MFMA compute internally (threshold 7.16e-2 = 2% of |out|max allows it).
// R16 = R15 best (107.27us) + coalesced f32 GEMM epilogue (clone of the
// session-proven u16 LDS-transpose epilogue; per-wave 8KB, 2 halves, float4).

typedef unsigned short u16;
typedef unsigned int u32;
typedef __bf16 bf16x8 __attribute__((ext_vector_type(8)));
typedef unsigned short u16x8 __attribute__((ext_vector_type(8)));
typedef unsigned short u16x4 __attribute__((ext_vector_type(4)));
typedef float f32x4 __attribute__((ext_vector_type(4)));

#define B_ 2
#define S_ 2048
#define D_ 1024
#define H_ 16
#define DH_ 64
#define BS_ (B_ * S_)
#define N3_ (3 * D_)

__device__ __forceinline__ u16 f2bf(float f) {
  unsigned u = __float_as_uint(f);
  u += 0x7FFFu + ((u >> 16) & 1u);   // RNE
  return (u16)(u >> 16);
}
__device__ __forceinline__ float bf2f(u16 s) {
  return __uint_as_float(((unsigned)s) << 16);
}

// packed f32x2 -> bf16x2 (RNE) via official intrinsic; correctness proven in
// R10 (passed absmax 0.0156). .x -> low16.
__device__ __forceinline__ u32 pk2(float lo, float hi) {
  __hip_bfloat162 h = __float22bfloat162_rn(float2{lo, hi});
  union { __hip_bfloat162 h; u32 w; } c;
  c.h = h;
  return c.w;
}

// native 2^x (v_exp_f32, cdna4_isa §3: D = 2^S0). Pure-VALU asm: no
// scheduling hazard; cannot be lowered to a libcall. (R15 win: +1.5us)
__device__ __forceinline__ float ex2(float x) {
  float r;
  asm("v_exp_f32 %0, %1" : "=v"(r) : "v"(x));
  return r;
}

union BU { u16x8 u; bf16x8 b; u32 w[4]; };
union BU4 { u16x4 u; u32 w[2]; };

// 3-input max; clang fuses nested fmaxf into v_max3_f32 (T17)
__device__ __forceinline__ float max3(float a, float b, float c) {
  return fmaxf(fmaxf(a, b), c);
}

// async global->LDS, 16B per lane. LDS dest = wave-uniform base + lane*16
// (linear); swizzling is done by permuting the per-lane GLOBAL source address.
__device__ __forceinline__ void gl16(const void* g, void* l) {
  __builtin_amdgcn_global_load_lds(
      (const __attribute__((address_space(1))) u32*)g,
      (__attribute__((address_space(3))) u32*)l, 16, 0, 0);
}

// ---------------- fused prologue: cvt(x), cvt_T(wqkv), cvt_T(wproj), tab ----
__global__ __launch_bounds__(256) void k_pre(const float* __restrict__ x,
                                             const float* __restrict__ wqkv,
                                             const float* __restrict__ wproj,
                                             u16* __restrict__ xb,
                                             u16* __restrict__ wqkvT,
                                             u16* __restrict__ wprojT,
                                             float* __restrict__ ct,
                                             float* __restrict__ st) {
  __shared__ float tl[32][33];
  const int bid = blockIdx.x;
  const int t = threadIdx.x;
  if (bid < 4096) {                       // ---- x -> bf16
    const int i = bid * 256 + t;
    const float4 f = ((const float4*)x)[i];
    BU4 o;
    o.w[0] = pk2(f.x, f.y);
    o.w[1] = pk2(f.z, f.w);
    *(u16x4*)(xb + (size_t)i * 4) = o.u;
    return;
  }
  if (bid < 8192) {                       // ---- weight transpose-convert
    const float* w; u16* wT; int R, C, bx, by;
    if (bid < 7168) {
      w = wqkv; wT = wqkvT; R = D_; C = N3_;
      const int id2 = bid - 4096; bx = id2 % 96; by = id2 / 96;
    } else {
      w = wproj; wT = wprojT; R = D_; C = D_;
      const int id2 = bid - 7168; bx = id2 % 32; by = id2 / 32;
    }
    const int lrow = t >> 3, seg = t & 7;
    const int r0 = by * 32, c0 = bx * 32;
    const float4 f = *(const float4*)(w + (size_t)(r0 + lrow) * C + c0 + seg * 4);
    tl[lrow][seg * 4 + 0] = f.x; tl[lrow][seg * 4 + 1] = f.y;
    tl[lrow][seg * 4 + 2] = f.z; tl[lrow][seg * 4 + 3] = f.w;
    __syncthreads();
    BU4 o;
    o.w[0] = pk2(tl[seg * 4 + 0][lrow], tl[seg * 4 + 1][lrow]);
    o.w[1] = pk2(tl[seg * 4 + 2][lrow], tl[seg * 4 + 3][lrow]);
    *(u16x4*)(wT + (size_t)(c0 + lrow) * R + r0 + seg * 4) = o.u;
    return;
  }
  {                                       // ---- cos/sin table (S x 32 fp32)
    const int idx = (bid - 8192) * 256 + t;
    const int tpos = idx >> 5, i = idx & 31;
    const float invf = powf(10000.0f, -(float)i * (1.0f / 32.0f));
    const float a = (float)tpos * invf;
    ct[idx] = cosf(a);
    st[idx] = sinf(a);
  }
}

// ---------------- bf16 GEMM: C[MxN] = A[MxK] * BT[NxK]^T ----------------
// 128x128 tile, 4 waves (2x2), 4x4 16x16x32 frags/wave. global_load_lds
// staging (linear LDS rows of 64B, source pre-swizzled slot^=(row>>1)&3),
// double-buffered, one barrier per K-step. Bijective XCD chunking.
// Both output dtypes use a coalesced LDS-transpose epilogue.
template <typename OutT>
__global__ __launch_bounds__(256) void k_gemm(const u16* __restrict__ A,
                                              const u16* __restrict__ BT,
                                              OutT* __restrict__ C,
                                              int M, int N, int K, int nbx) {
  __shared__ u16 smem[16384];   // [A bufs 2x4096 | B bufs 2x4096] / epilogue
  u16* laA = smem;
  u16* laB = smem + 8192;
  const int t = threadIdx.x;
  const int per_x = gridDim.x >> 3;
  const int nid = (blockIdx.x & 7) * per_x + (blockIdx.x >> 3);
  const int n0 = (nid % nbx) * 128, m0 = (nid / nbx) * 128;
  const int w = t >> 6, lane = t & 63;
  const int lr = lane & 15, lg = lane >> 4;
  const int wm = (w >> 1) * 64, wn = (w & 1) * 64;
  const int NK = K >> 5;

  const int srow = lane >> 2;
  const int sc = ((lane & 3) ^ ((lane >> 3) & 3)) * 8;   // element offset
  const u16* Ag = A + (size_t)(m0 + w * 32 + srow) * K + sc;
  const u16* Bg = BT + (size_t)(n0 + w * 32 + srow) * K + sc;
  const int ldsw = w * 1024;

  f32x4 acc[4][4] = {};

#pragma unroll
  for (int i = 0; i < 2; ++i) {
    gl16(Ag + (size_t)i * 16 * K, laA + ldsw + i * 512);
    gl16(Bg + (size_t)i * 16 * K, laB + ldsw + i * 512);
  }
  __syncthreads();

  int cur = 0;
  for (int kt = 0; kt < NK; ++kt) {
    if (kt + 1 < NK) {
      const int ko = (kt + 1) * 32;
#pragma unroll
      for (int i = 0; i < 2; ++i) {
        gl16(Ag + (size_t)i * 16 * K + ko, laA + (cur ^ 1) * 4096 + ldsw + i * 512);
        gl16(Bg + (size_t)i * 16 * K + ko, laB + (cur ^ 1) * 4096 + ldsw + i * 512);
      }
    }
    const char* pa = (const char*)(laA + cur * 4096);
    const char* pb = (const char*)(laB + cur * 4096);
    BU af[4], bfr[4];
    const int rsw = ((lr >> 1) & 3);
#pragma unroll
    for (int mi = 0; mi < 4; ++mi) {
      const int ra = wm + mi * 16 + lr;
      af[mi].u = *(const u16x8*)(pa + ra * 64 + ((lg ^ rsw) * 16));
      const int rb = wn + mi * 16 + lr;
      bfr[mi].u = *(const u16x8*)(pb + rb * 64 + ((lg ^ rsw) * 16));
    }
#pragma unroll
    for (int mi = 0; mi < 4; ++mi)
#pragma unroll
      for (int ni = 0; ni < 4; ++ni)
        acc[mi][ni] = __builtin_amdgcn_mfma_f32_16x16x32_bf16(af[mi].b, bfr[ni].b,
                                                              acc[mi][ni], 0, 0, 0);
    __syncthreads();
    cur ^= 1;
  }

  // C/D layout: col = lane&15, row = (lane>>4)*4 + reg  (m89-verified)
  if constexpr (sizeof(OutT) == 2) {
    // coalesced epilogue: wave tile -> LDS (64x64 u16) -> u16x8 stores
    u16* ew = smem + w * 4096;
#pragma unroll
    for (int mi = 0; mi < 4; ++mi)
#pragma unroll
      for (int ni = 0; ni < 4; ++ni)
#pragma unroll
        for (int r = 0; r < 4; ++r)
          ew[(mi * 16 + lg * 4 + r) * 64 + ni * 16 + lr] = f2bf(acc[mi][ni][r]);
    const int er = lane >> 3, es = (lane & 7) * 8;
#pragma unroll
    for (int pass = 0; pass < 8; ++pass) {
      const int row = pass * 8 + er;
      const u16x8 v = *(const u16x8*)(ew + row * 64 + es);
      *(u16x8*)((u16*)C + (size_t)(m0 + wm + row) * N + n0 + wn + es) = v;
    }
  } else {
    // coalesced f32 epilogue: per-wave 8KB LDS region, 2 halves of 32 rows,
    // float4 stores (16 lanes x 16B = 256B contiguous per row).
    float* fw = (float*)(smem + w * 4096);
    const int er = lane >> 4, es = (lane & 15) * 4;
#pragma unroll
    for (int h = 0; h < 2; ++h) {
#pragma unroll
      for (int q = 0; q < 2; ++q)
#pragma unroll
        for (int ni = 0; ni < 4; ++ni)
#pragma unroll
          for (int r = 0; r < 4; ++r)
            fw[(q * 16 + lg * 4 + r) * 64 + ni * 16 + lr] = acc[h * 2 + q][ni][r];
#pragma unroll
      for (int p = 0; p < 8; ++p) {
        const int row = p * 4 + er;
        const float4 v = *(const float4*)(fw + row * 64 + es);
        *(float4*)((float*)C + (size_t)(m0 + wm + h * 32 + row) * N + n0 + wn + es) = v;
      }
    }
  }
}

// ---------------- RoPE + head layout + V transpose ----------------
// qkv (BS x 3072) bf16 -> Q (pre-scaled by log2e/8 for exp2-domain softmax),
// K [bh][s][dh], Vt [bh][dh][s]. XCD-pinned: bid&7 == bh%8 (matches k_attn).
__global__ __launch_bounds__(256) void k_prep(const u16* __restrict__ qkv,
                                              const float* __restrict__ ct,
                                              const float* __restrict__ st,
                                              u16* __restrict__ Q, u16* __restrict__ K,
                                              u16* __restrict__ Vt) {
  __shared__ u16 vl[64][72];
  const int bid = blockIdx.x;
  const int xcd = bid & 7, slot = bid >> 3;
  const int bh = xcd + 8 * (slot >> 5);
  const int stile = slot & 31;
  const int b = bh >> 4, h = bh & 15;
  const int t = threadIdx.x;
  const int row = t >> 2, qr = t & 3;
  const int s = stile * 64 + row;
  const u16* base = qkv + (size_t)(b * S_ + s) * N3_ + h * DH_;
  const int d0 = qr * 8;  // pair-halves d0..d0+7 and +32
  float c[8], sn[8];
#pragma unroll
  for (int j = 0; j < 8; ++j) {
    c[j] = ct[s * 32 + d0 + j];
    sn[j] = st[s * 32 + d0 + j];
  }
#pragma unroll
  for (int part = 0; part < 2; ++part) {
    // fold 1/sqrt(Dh) * log2(e) into Q: softmax uses raw v_exp_f32 (2^x).
    const float qs = (part == 0) ? 0.125f * 1.44269504f : 1.0f;
    const u16* src = base + part * D_;
    u16x8 lo = *(const u16x8*)(src + d0);
    u16x8 hi = *(const u16x8*)(src + d0 + 32);
    float ylo[8], yhi[8];
#pragma unroll
    for (int j = 0; j < 8; ++j) {
      float x1 = bf2f(lo[j]) * qs, x2 = bf2f(hi[j]) * qs;
      ylo[j] = x1 * c[j] - x2 * sn[j];
      yhi[j] = x2 * c[j] + x1 * sn[j];
    }
    BU olo, ohi;
#pragma unroll
    for (int jj = 0; jj < 4; ++jj) {
      olo.w[jj] = pk2(ylo[jj * 2], ylo[jj * 2 + 1]);
      ohi.w[jj] = pk2(yhi[jj * 2], yhi[jj * 2 + 1]);
    }
    u16* dst = (part ? K : Q) + ((size_t)bh * S_ + s) * DH_;
    *(u16x8*)(dst + d0) = olo.u;
    *(u16x8*)(dst + d0 + 32) = ohi.u;
  }
  // V transpose through LDS (64 s-rows x 64 dh -> 64 dh-rows x 64 s)
  u16x8 v0 = *(const u16x8*)(base + 2 * D_ + qr * 16);
  u16x8 v1 = *(const u16x8*)(base + 2 * D_ + qr * 16 + 8);
#pragma unroll
  for (int j = 0; j < 8; ++j) {
    vl[qr * 16 + j][row] = v0[j];
    vl[qr * 16 + 8 + j][row] = v1[j];
  }
  __syncthreads();
  const int dh = row, sc = qr * 16;
  u16x8 o0, o1;
#pragma unroll
  for (int j = 0; j < 8; ++j) { o0[j] = vl[dh][sc + j]; o1[j] = vl[dh][sc + 8 + j]; }
  u16* vdst = Vt + ((size_t)bh * DH_ + dh) * S_ + stile * 64 + sc;
  *(u16x8*)vdst = o0;
  *(u16x8*)(vdst + 8) = o1;
}

// ---------------- causal flash attention (R15 best) -----------------------
// 1024 blocks of 4 waves, block = (bh, 64-row q-tile), longest first,
// XCD-pinned. K/V staged via global_load_lds, double-buffered. K-tile rows
// LDS-PERMUTED by perm(a)=a4<<5|a3a2<<3|a5<<2|a1a0 so each lane holds the 16
// P-values its own PV B-fragments need. Lane-local softmax in log2 domain
// (Q pre-scaled by log2e/8; raw v_exp_f32); T13 defer-max THR=11.5 (== e-dom
// 8); l reduced once at end; T5 setprio; T17 v_max3; pk2 packed conversions.
__global__ __launch_bounds__(256, 2) void k_attn(const u16* __restrict__ Q,
                                                 const u16* __restrict__ K,
                                                 const u16* __restrict__ Vt,
                                                 u16* __restrict__ Ao) {
  __shared__ char kvb_[2][16384];   // per buf: K tile [64][128B] @0, V^T tile @8192
  const int bid = blockIdx.x;
  const int xcd = bid & 7, inner = bid >> 3;
  const int bh = xcd + 8 * (inner & 3);
  const int qt = 31 - (inner >> 2);          // longest first
  const int t = threadIdx.x;
  const int w = t >> 6, lane = t & 63;
  const int lr = lane & 15, lg = lane >> 4;
  const int q0 = qt * 64 + w * 16;
  const int nt = qt + 1;

  const u16* Kbh = K + (size_t)bh * S_ * DH_;
  const u16* Vbh = Vt + (size_t)bh * DH_ * S_;

  const int sr = lane >> 3;                  // 0..7
  const int sc = ((lane & 7) ^ sr) * 8;      // element offset, pre-swizzled
  char* kd0 = kvb_[0] + w * 2048;            // + j*1024 ; +8192 for V
  char* kd1 = kvb_[1] + w * 2048;
  int prow[2], vrow[2];
#pragma unroll
  for (int j = 0; j < 2; ++j) {
    const int a = w * 16 + j * 8 + sr;
    prow[j] = (((a >> 4) & 1) << 5) | (((a >> 2) & 3) << 3) |
              (((a >> 5) & 1) << 2) | (a & 3);
    vrow[j] = a;
  }

  const u16* Qb = Q + ((size_t)bh * S_ + q0) * DH_;
  BU qf0, qf1;                   // B-operand: Q^T[d=lg*8+j][q=lr]
  qf0.u = *(const u16x8*)(Qb + lr * DH_ + lg * 8);
  qf1.u = *(const u16x8*)(Qb + lr * DH_ + 32 + lg * 8);

  f32x4 o[4] = {};               // O^T acc: o[d] dh=d*16+lg*4+r, q=lr
  float m = -1e30f, l = 0.f;

#pragma unroll
  for (int j = 0; j < 2; ++j) {  // stage tile 0 -> buf 0
    gl16(Kbh + (size_t)prow[j] * DH_ + sc, kd0 + j * 1024);
    gl16(Vbh + (size_t)vrow[j] * S_ + sc, kd0 + 8192 + j * 1024);
  }
  __syncthreads();

  int cur = 0;
  for (int it = 0; it < nt; ++it) {
    const int kv0 = it * 64;
    const bool more = (it + 1 < nt);
    if (more) {                  // async prefetch next tile
      const int kvn = kv0 + 64;
      char* nd = cur ? kd0 : kd1;
#pragma unroll
      for (int j = 0; j < 2; ++j) {
        gl16(Kbh + (size_t)(kvn + prow[j]) * DH_ + sc, nd + j * 1024);
        gl16(Vbh + (size_t)vrow[j] * S_ + kvn + sc, nd + 8192 + j * 1024);
      }
    }
    const char* base = kvb_[cur];
    f32x4 s[4] = {};
    __builtin_amdgcn_s_setprio(1);   // T5: favor MFMA-entering wave
#pragma unroll
    for (int kvbi = 0; kvbi < 4; ++kvbi) {
      const int row = kvbi * 16 + lr;
      const int sw = (lr & 7) << 4;
      BU k0, k1;
      k0.u = *(const u16x8*)(base + row * 128 + ((lg * 16) ^ sw));
      k1.u = *(const u16x8*)(base + row * 128 + ((64 + lg * 16) ^ sw));
      s[kvbi] = __builtin_amdgcn_mfma_f32_16x16x32_bf16(k0.b, qf0.b, s[kvbi], 0, 0, 0);
      s[kvbi] = __builtin_amdgcn_mfma_f32_16x16x32_bf16(k1.b, qf1.b, s[kvbi], 0, 0, 0);
    }
    __builtin_amdgcn_s_setprio(0);
    // s[kvbi][r] = S[kv0 + truekv][q0+lr], truekv = (kvbi&1)*32+lg*8+(kvbi>>1)*4+r
    float p[16];
#pragma unroll
    for (int kvbi = 0; kvbi < 4; ++kvbi)
#pragma unroll
      for (int r = 0; r < 4; ++r) p[kvbi * 4 + r] = s[kvbi][r];
    if (it == nt - 1) {          // only diagonal-crossing tile masks
#pragma unroll
      for (int kvbi = 0; kvbi < 4; ++kvbi)
#pragma unroll
        for (int r = 0; r < 4; ++r) {
          const int tkv = ((kvbi & 1) << 5) + lg * 8 + ((kvbi >> 1) << 2) + r;
          if (kv0 + tkv > q0 + lr) p[kvbi * 4 + r] = -1e30f;
        }
    }
    // in-lane max tree via v_max3 (T17)
    const float m0_ = max3(p[0], p[1], p[2]);
    const float m1_ = max3(p[3], p[4], p[5]);
    const float m2_ = max3(p[6], p[7], p[8]);
    const float m3_ = max3(p[9], p[10], p[11]);
    const float m4_ = max3(p[12], p[13], p[14]);
    const float mx = fmaxf(max3(m0_, m1_, m2_), max3(m3_, m4_, p[15]));
    // defer-max (T13): log2-domain THR 11.5 == e-domain 8
    if (__any(mx > m + 11.5f)) {
      float cm = mx;
      cm = fmaxf(cm, __shfl_xor(cm, 16, 64));
      cm = fmaxf(cm, __shfl_xor(cm, 32, 64));
      const float mn = fmaxf(m, cm);
      const float al = ex2(m - mn);
      m = mn;
      l *= al;
#pragma unroll
      for (int d = 0; d < 4; ++d)
#pragma unroll
        for (int r = 0; r < 4; ++r) o[d][r] *= al;
    }
#pragma unroll
    for (int i = 0; i < 16; ++i) p[i] = ex2(p[i] - m);
    {  // in-lane partial sum; cross-lane reduce deferred to epilogue
      float s0 = (p[0] + p[1]) + (p[2] + p[3]);
      float s1 = (p[4] + p[5]) + (p[6] + p[7]);
      float s2 = (p[8] + p[9]) + (p[10] + p[11]);
      float s3 = (p[12] + p[13]) + (p[14] + p[15]);
      l += (s0 + s1) + (s2 + s3);
    }
    // PV B-fragments fully in-lane via packed cvt (pk2, R10-proven):
    // pf0[j]=P[lg*8+j], pf1[j]=P[32+lg*8+j]
    BU pf0, pf1;
    pf0.w[0] = pk2(p[0], p[1]);   pf0.w[1] = pk2(p[2], p[3]);
    pf0.w[2] = pk2(p[8], p[9]);   pf0.w[3] = pk2(p[10], p[11]);
    pf1.w[0] = pk2(p[4], p[5]);   pf1.w[1] = pk2(p[6], p[7]);
    pf1.w[2] = pk2(p[12], p[13]); pf1.w[3] = pk2(p[14], p[15]);
    __builtin_amdgcn_s_setprio(1);   // T5 around PV cluster
#pragma unroll
    for (int d = 0; d < 4; ++d) {
      const int row = d * 16 + lr;
      const int sw = (lr & 7) << 4;
      BU v0, v1;
      v0.u = *(const u16x8*)(base + 8192 + row * 128 + ((lg * 16) ^ sw));
      v1.u = *(const u16x8*)(base + 8192 + row * 128 + ((64 + lg * 16) ^ sw));
      o[d] = __builtin_amdgcn_mfma_f32_16x16x32_bf16(v0.b, pf0.b, o[d], 0, 0, 0);
      o[d] = __builtin_amdgcn_mfma_f32_16x16x32_bf16(v1.b, pf1.b, o[d], 0, 0, 0);
    }
    __builtin_amdgcn_s_setprio(0);
    if (more) __syncthreads();   // block-uniform; last iter needs no barrier
    cur ^= 1;
  }

  l += __shfl_xor(l, 16, 64);
  l += __shfl_xor(l, 32, 64);
  const float inv = 1.0f / l;
  const int b = bh >> 4, h = bh & 15;
  const size_t rowo = ((size_t)b * S_ + q0 + lr) * D_ + h * DH_;
#pragma unroll
  for (int d = 0; d < 4; ++d) {
    BU4 w4;
    w4.w[0] = pk2(o[d][0] * inv, o[d][1] * inv);
    w4.w[1] = pk2(o[d][2] * inv, o[d][3] * inv);
    *(u16x4*)(Ao + rowo + d * 16 + lg * 4) = w4.u;
  }
}

// ---------------- launch ----------------
extern "C" void kernel_launch(void* const* d_in, const int* in_sizes, int n_in,
                              void* d_out, int out_size, void* d_ws, size_t ws_size,
                              hipStream_t stream) {
  const float* x = (const float*)d_in[0];
  const float* wqkv = (const float*)d_in[1];
  const float* wproj = (const float*)d_in[2];
  float* out = (float*)d_out;
  char* ws = (char*)d_ws;

  // workspace layout (~76 MB total)
  u16* xb      = (u16*)(ws + 0);          //  8 MB  x bf16 (4096x1024)
  u16* wqkvT   = (u16*)(ws + 8388608);    //  6 MB  w_qkv^T bf16 (3072x1024)
  u16* wprojT  = (u16*)(ws + 14680064);   //  2 MB  w_proj^T bf16 (1024x1024)
  u16* qkvb    = (u16*)(ws + 16777216);   // 24 MB  qkv bf16 (4096x3072)
  u16* Qb      = (u16*)(ws + 41943040);   //  8 MB  [bh][s][dh], pre-scaled
  u16* Kb      = (u16*)(ws + 50331648);   //  8 MB  [bh][s][dh]
  u16* Vtb     = (u16*)(ws + 58720256);   //  8 MB  [bh][dh][s]
  u16* aob     = (u16*)(ws + 67108864);   //  8 MB  attn out (4096x1024)
  float* ct    = (float*)(ws + 75497472); // 256 KB cos table (S x 32)
  float* stab  = (float*)(ws + 75759616); // 256 KB sin table

  k_pre<<<8448, 256, 0, stream>>>(x, wqkv, wproj, xb, wqkvT, wprojT, ct, stab);
  k_gemm<u16><<<768, 256, 0, stream>>>(xb, wqkvT, qkvb, BS_, N3_, D_, 24);
  k_prep<<<1024, 256, 0, stream>>>(qkvb, ct, stab, Qb, Kb, Vtb);
  k_attn<<<1024, 256, 0, stream>>>(Qb, Kb, Vtb, aob);
  k_gemm<float><<<256, 256, 0, stream>>>(aob, wprojT, out, BS_, D_, D_, 8);
}

// Round 17
// 107.133 us; speedup vs baseline: 1.0028x; 1.0028x over previous
//
#include <hip/hip_runtime.h>
#include <hip/hip_bf16.h>

// MultiHeadAttentionRoPE: B=2,S=2048,D=1024,H=16,Dh=64 causal, fp32 in/out,
// bf16 MFMA compute internally (threshold 7.16e-2 = 2% of |out|max allows it).
// FINAL = R15 best (107.27us): R12 structure + final-barrier skip + raw
// v_exp_f32 exp2-domain softmax. R16's f32-epilogue experiment was neutral
// and is reverted. Session: 306 -> 107 us (2.86x).

typedef unsigned short u16;
typedef unsigned int u32;
typedef __bf16 bf16x8 __attribute__((ext_vector_type(8)));
typedef unsigned short u16x8 __attribute__((ext_vector_type(8)));
typedef unsigned short u16x4 __attribute__((ext_vector_type(4)));
typedef float f32x4 __attribute__((ext_vector_type(4)));

#define B_ 2
#define S_ 2048
#define D_ 1024
#define H_ 16
#define DH_ 64
#define BS_ (B_ * S_)
#define N3_ (3 * D_)

__device__ __forceinline__ u16 f2bf(float f) {
  unsigned u = __float_as_uint(f);
  u += 0x7FFFu + ((u >> 16) & 1u);   // RNE
  return (u16)(u >> 16);
}
__device__ __forceinline__ float bf2f(u16 s) {
  return __uint_as_float(((unsigned)s) << 16);
}

// packed f32x2 -> bf16x2 (RNE) via official intrinsic; correctness proven in
// R10 (passed absmax 0.0156). .x -> low16.
__device__ __forceinline__ u32 pk2(float lo, float hi) {
  __hip_bfloat162 h = __float22bfloat162_rn(float2{lo, hi});
  union { __hip_bfloat162 h; u32 w; } c;
  c.h = h;
  return c.w;
}

// native 2^x (v_exp_f32, cdna4_isa §3: D = 2^S0). Pure-VALU asm: no
// scheduling hazard; cannot be lowered to a libcall. (R15 win: +1.5us)
__device__ __forceinline__ float ex2(float x) {
  float r;
  asm("v_exp_f32 %0, %1" : "=v"(r) : "v"(x));
  return r;
}

union BU { u16x8 u; bf16x8 b; u32 w[4]; };
union BU4 { u16x4 u; u32 w[2]; };

// 3-input max; clang fuses nested fmaxf into v_max3_f32 (T17)
__device__ __forceinline__ float max3(float a, float b, float c) {
  return fmaxf(fmaxf(a, b), c);
}

// async global->LDS, 16B per lane. LDS dest = wave-uniform base + lane*16
// (linear); swizzling is done by permuting the per-lane GLOBAL source address.
__device__ __forceinline__ void gl16(const void* g, void* l) {
  __builtin_amdgcn_global_load_lds(
      (const __attribute__((address_space(1))) u32*)g,
      (__attribute__((address_space(3))) u32*)l, 16, 0, 0);
}

// ---------------- fused prologue: cvt(x), cvt_T(wqkv), cvt_T(wproj), tab ----
__global__ __launch_bounds__(256) void k_pre(const float* __restrict__ x,
                                             const float* __restrict__ wqkv,
                                             const float* __restrict__ wproj,
                                             u16* __restrict__ xb,
                                             u16* __restrict__ wqkvT,
                                             u16* __restrict__ wprojT,
                                             float* __restrict__ ct,
                                             float* __restrict__ st) {
  __shared__ float tl[32][33];
  const int bid = blockIdx.x;
  const int t = threadIdx.x;
  if (bid < 4096) {                       // ---- x -> bf16
    const int i = bid * 256 + t;
    const float4 f = ((const float4*)x)[i];
    BU4 o;
    o.w[0] = pk2(f.x, f.y);
    o.w[1] = pk2(f.z, f.w);
    *(u16x4*)(xb + (size_t)i * 4) = o.u;
    return;
  }
  if (bid < 8192) {                       // ---- weight transpose-convert
    const float* w; u16* wT; int R, C, bx, by;
    if (bid < 7168) {
      w = wqkv; wT = wqkvT; R = D_; C = N3_;
      const int id2 = bid - 4096; bx = id2 % 96; by = id2 / 96;
    } else {
      w = wproj; wT = wprojT; R = D_; C = D_;
      const int id2 = bid - 7168; bx = id2 % 32; by = id2 / 32;
    }
    const int lrow = t >> 3, seg = t & 7;
    const int r0 = by * 32, c0 = bx * 32;
    const float4 f = *(const float4*)(w + (size_t)(r0 + lrow) * C + c0 + seg * 4);
    tl[lrow][seg * 4 + 0] = f.x; tl[lrow][seg * 4 + 1] = f.y;
    tl[lrow][seg * 4 + 2] = f.z; tl[lrow][seg * 4 + 3] = f.w;
    __syncthreads();
    BU4 o;
    o.w[0] = pk2(tl[seg * 4 + 0][lrow], tl[seg * 4 + 1][lrow]);
    o.w[1] = pk2(tl[seg * 4 + 2][lrow], tl[seg * 4 + 3][lrow]);
    *(u16x4*)(wT + (size_t)(c0 + lrow) * R + r0 + seg * 4) = o.u;
    return;
  }
  {                                       // ---- cos/sin table (S x 32 fp32)
    const int idx = (bid - 8192) * 256 + t;
    const int tpos = idx >> 5, i = idx & 31;
    const float invf = powf(10000.0f, -(float)i * (1.0f / 32.0f));
    const float a = (float)tpos * invf;
    ct[idx] = cosf(a);
    st[idx] = sinf(a);
  }
}

// ---------------- bf16 GEMM: C[MxN] = A[MxK] * BT[NxK]^T ----------------
// 128x128 tile, 4 waves (2x2), 4x4 16x16x32 frags/wave. global_load_lds
// staging (linear LDS rows of 64B, source pre-swizzled slot^=(row>>1)&3),
// double-buffered, one barrier per K-step. Bijective XCD chunking.
template <typename OutT>
__global__ __launch_bounds__(256) void k_gemm(const u16* __restrict__ A,
                                              const u16* __restrict__ BT,
                                              OutT* __restrict__ C,
                                              int M, int N, int K, int nbx) {
  __shared__ u16 smem[16384];   // [A bufs 2x4096 | B bufs 2x4096] / epilogue
  u16* laA = smem;
  u16* laB = smem + 8192;
  const int t = threadIdx.x;
  const int per_x = gridDim.x >> 3;
  const int nid = (blockIdx.x & 7) * per_x + (blockIdx.x >> 3);
  const int n0 = (nid % nbx) * 128, m0 = (nid / nbx) * 128;
  const int w = t >> 6, lane = t & 63;
  const int lr = lane & 15, lg = lane >> 4;
  const int wm = (w >> 1) * 64, wn = (w & 1) * 64;
  const int NK = K >> 5;

  const int srow = lane >> 2;
  const int sc = ((lane & 3) ^ ((lane >> 3) & 3)) * 8;   // element offset
  const u16* Ag = A + (size_t)(m0 + w * 32 + srow) * K + sc;
  const u16* Bg = BT + (size_t)(n0 + w * 32 + srow) * K + sc;
  const int ldsw = w * 1024;

  f32x4 acc[4][4] = {};

#pragma unroll
  for (int i = 0; i < 2; ++i) {
    gl16(Ag + (size_t)i * 16 * K, laA + ldsw + i * 512);
    gl16(Bg + (size_t)i * 16 * K, laB + ldsw + i * 512);
  }
  __syncthreads();

  int cur = 0;
  for (int kt = 0; kt < NK; ++kt) {
    if (kt + 1 < NK) {
      const int ko = (kt + 1) * 32;
#pragma unroll
      for (int i = 0; i < 2; ++i) {
        gl16(Ag + (size_t)i * 16 * K + ko, laA + (cur ^ 1) * 4096 + ldsw + i * 512);
        gl16(Bg + (size_t)i * 16 * K + ko, laB + (cur ^ 1) * 4096 + ldsw + i * 512);
      }
    }
    const char* pa = (const char*)(laA + cur * 4096);
    const char* pb = (const char*)(laB + cur * 4096);
    BU af[4], bfr[4];
    const int rsw = ((lr >> 1) & 3);
#pragma unroll
    for (int mi = 0; mi < 4; ++mi) {
      const int ra = wm + mi * 16 + lr;
      af[mi].u = *(const u16x8*)(pa + ra * 64 + ((lg ^ rsw) * 16));
      const int rb = wn + mi * 16 + lr;
      bfr[mi].u = *(const u16x8*)(pb + rb * 64 + ((lg ^ rsw) * 16));
    }
#pragma unroll
    for (int mi = 0; mi < 4; ++mi)
#pragma unroll
      for (int ni = 0; ni < 4; ++ni)
        acc[mi][ni] = __builtin_amdgcn_mfma_f32_16x16x32_bf16(af[mi].b, bfr[ni].b,
                                                              acc[mi][ni], 0, 0, 0);
    __syncthreads();
    cur ^= 1;
  }

  // C/D layout: col = lane&15, row = (lane>>4)*4 + reg  (m89-verified)
  if constexpr (sizeof(OutT) == 2) {
    // coalesced epilogue: wave tile -> LDS (64x64 u16) -> u16x8 stores
    u16* ew = smem + w * 4096;
#pragma unroll
    for (int mi = 0; mi < 4; ++mi)
#pragma unroll
      for (int ni = 0; ni < 4; ++ni)
#pragma unroll
        for (int r = 0; r < 4; ++r)
          ew[(mi * 16 + lg * 4 + r) * 64 + ni * 16 + lr] = f2bf(acc[mi][ni][r]);
    const int er = lane >> 3, es = (lane & 7) * 8;
#pragma unroll
    for (int pass = 0; pass < 8; ++pass) {
      const int row = pass * 8 + er;
      const u16x8 v = *(const u16x8*)(ew + row * 64 + es);
      *(u16x8*)((u16*)C + (size_t)(m0 + wm + row) * N + n0 + wn + es) = v;
    }
  } else {
#pragma unroll
    for (int mi = 0; mi < 4; ++mi)
#pragma unroll
      for (int ni = 0; ni < 4; ++ni)
#pragma unroll
        for (int r = 0; r < 4; ++r) {
          const int row = m0 + wm + mi * 16 + lg * 4 + r;
          const int col = n0 + wn + ni * 16 + lr;
          ((float*)C)[(size_t)row * N + col] = acc[mi][ni][r];
        }
  }
}

// ---------------- RoPE + head layout + V transpose ----------------
// qkv (BS x 3072) bf16 -> Q (pre-scaled by log2e/8 for exp2-domain softmax),
// K [bh][s][dh], Vt [bh][dh][s]. XCD-pinned: bid&7 == bh%8 (matches k_attn).
__global__ __launch_bounds__(256) void k_prep(const u16* __restrict__ qkv,
                                              const float* __restrict__ ct,
                                              const float* __restrict__ st,
                                              u16* __restrict__ Q, u16* __restrict__ K,
                                              u16* __restrict__ Vt) {
  __shared__ u16 vl[64][72];
  const int bid = blockIdx.x;
  const int xcd = bid & 7, slot = bid >> 3;
  const int bh = xcd + 8 * (slot >> 5);
  const int stile = slot & 31;
  const int b = bh >> 4, h = bh & 15;
  const int t = threadIdx.x;
  const int row = t >> 2, qr = t & 3;
  const int s = stile * 64 + row;
  const u16* base = qkv + (size_t)(b * S_ + s) * N3_ + h * DH_;
  const int d0 = qr * 8;  // pair-halves d0..d0+7 and +32
  float c[8], sn[8];
#pragma unroll
  for (int j = 0; j < 8; ++j) {
    c[j] = ct[s * 32 + d0 + j];
    sn[j] = st[s * 32 + d0 + j];
  }
#pragma unroll
  for (int part = 0; part < 2; ++part) {
    // fold 1/sqrt(Dh) * log2(e) into Q: softmax uses raw v_exp_f32 (2^x).
    const float qs = (part == 0) ? 0.125f * 1.44269504f : 1.0f;
    const u16* src = base + part * D_;
    u16x8 lo = *(const u16x8*)(src + d0);
    u16x8 hi = *(const u16x8*)(src + d0 + 32);
    float ylo[8], yhi[8];
#pragma unroll
    for (int j = 0; j < 8; ++j) {
      float x1 = bf2f(lo[j]) * qs, x2 = bf2f(hi[j]) * qs;
      ylo[j] = x1 * c[j] - x2 * sn[j];
      yhi[j] = x2 * c[j] + x1 * sn[j];
    }
    BU olo, ohi;
#pragma unroll
    for (int jj = 0; jj < 4; ++jj) {
      olo.w[jj] = pk2(ylo[jj * 2], ylo[jj * 2 + 1]);
      ohi.w[jj] = pk2(yhi[jj * 2], yhi[jj * 2 + 1]);
    }
    u16* dst = (part ? K : Q) + ((size_t)bh * S_ + s) * DH_;
    *(u16x8*)(dst + d0) = olo.u;
    *(u16x8*)(dst + d0 + 32) = ohi.u;
  }
  // V transpose through LDS (64 s-rows x 64 dh -> 64 dh-rows x 64 s)
  u16x8 v0 = *(const u16x8*)(base + 2 * D_ + qr * 16);
  u16x8 v1 = *(const u16x8*)(base + 2 * D_ + qr * 16 + 8);
#pragma unroll
  for (int j = 0; j < 8; ++j) {
    vl[qr * 16 + j][row] = v0[j];
    vl[qr * 16 + 8 + j][row] = v1[j];
  }
  __syncthreads();
  const int dh = row, sc = qr * 16;
  u16x8 o0, o1;
#pragma unroll
  for (int j = 0; j < 8; ++j) { o0[j] = vl[dh][sc + j]; o1[j] = vl[dh][sc + 8 + j]; }
  u16* vdst = Vt + ((size_t)bh * DH_ + dh) * S_ + stile * 64 + sc;
  *(u16x8*)vdst = o0;
  *(u16x8*)(vdst + 8) = o1;
}

// ---------------- causal flash attention (session best) -------------------
// 1024 blocks of 4 waves, block = (bh, 64-row q-tile), longest first,
// XCD-pinned. K/V staged via global_load_lds, double-buffered. K-tile rows
// LDS-PERMUTED by perm(a)=a4<<5|a3a2<<3|a5<<2|a1a0 so each lane holds the 16
// P-values its own PV B-fragments need. Lane-local softmax in log2 domain
// (Q pre-scaled by log2e/8; raw v_exp_f32); T13 defer-max THR=11.5 (== e-dom
// 8); l reduced once at end; T5 setprio; T17 v_max3; pk2 packed conversions.
__global__ __launch_bounds__(256, 2) void k_attn(const u16* __restrict__ Q,
                                                 const u16* __restrict__ K,
                                                 const u16* __restrict__ Vt,
                                                 u16* __restrict__ Ao) {
  __shared__ char kvb_[2][16384];   // per buf: K tile [64][128B] @0, V^T tile @8192
  const int bid = blockIdx.x;
  const int xcd = bid & 7, inner = bid >> 3;
  const int bh = xcd + 8 * (inner & 3);
  const int qt = 31 - (inner >> 2);          // longest first
  const int t = threadIdx.x;
  const int w = t >> 6, lane = t & 63;
  const int lr = lane & 15, lg = lane >> 4;
  const int q0 = qt * 64 + w * 16;
  const int nt = qt + 1;

  const u16* Kbh = K + (size_t)bh * S_ * DH_;
  const u16* Vbh = Vt + (size_t)bh * DH_ * S_;

  const int sr = lane >> 3;                  // 0..7
  const int sc = ((lane & 7) ^ sr) * 8;      // element offset, pre-swizzled
  char* kd0 = kvb_[0] + w * 2048;            // + j*1024 ; +8192 for V
  char* kd1 = kvb_[1] + w * 2048;
  int prow[2], vrow[2];
#pragma unroll
  for (int j = 0; j < 2; ++j) {
    const int a = w * 16 + j * 8 + sr;
    prow[j] = (((a >> 4) & 1) << 5) | (((a >> 2) & 3) << 3) |
              (((a >> 5) & 1) << 2) | (a & 3);
    vrow[j] = a;
  }

  const u16* Qb = Q + ((size_t)bh * S_ + q0) * DH_;
  BU qf0, qf1;                   // B-operand: Q^T[d=lg*8+j][q=lr]
  qf0.u = *(const u16x8*)(Qb + lr * DH_ + lg * 8);
  qf1.u = *(const u16x8*)(Qb + lr * DH_ + 32 + lg * 8);

  f32x4 o[4] = {};               // O^T acc: o[d] dh=d*16+lg*4+r, q=lr
  float m = -1e30f, l = 0.f;

#pragma unroll
  for (int j = 0; j < 2; ++j) {  // stage tile 0 -> buf 0
    gl16(Kbh + (size_t)prow[j] * DH_ + sc, kd0 + j * 1024);
    gl16(Vbh + (size_t)vrow[j] * S_ + sc, kd0 + 8192 + j * 1024);
  }
  __syncthreads();

  int cur = 0;
  for (int it = 0; it < nt; ++it) {
    const int kv0 = it * 64;
    const bool more = (it + 1 < nt);
    if (more) {                  // async prefetch next tile
      const int kvn = kv0 + 64;
      char* nd = cur ? kd0 : kd1;
#pragma unroll
      for (int j = 0; j < 2; ++j) {
        gl16(Kbh + (size_t)(kvn + prow[j]) * DH_ + sc, nd + j * 1024);
        gl16(Vbh + (size_t)vrow[j] * S_ + kvn + sc, nd + 8192 + j * 1024);
      }
    }
    const char* base = kvb_[cur];
    f32x4 s[4] = {};
    __builtin_amdgcn_s_setprio(1);   // T5: favor MFMA-entering wave
#pragma unroll
    for (int kvbi = 0; kvbi < 4; ++kvbi) {
      const int row = kvbi * 16 + lr;
      const int sw = (lr & 7) << 4;
      BU k0, k1;
      k0.u = *(const u16x8*)(base + row * 128 + ((lg * 16) ^ sw));
      k1.u = *(const u16x8*)(base + row * 128 + ((64 + lg * 16) ^ sw));
      s[kvbi] = __builtin_amdgcn_mfma_f32_16x16x32_bf16(k0.b, qf0.b, s[kvbi], 0, 0, 0);
      s[kvbi] = __builtin_amdgcn_mfma_f32_16x16x32_bf16(k1.b, qf1.b, s[kvbi], 0, 0, 0);
    }
    __builtin_amdgcn_s_setprio(0);
    // s[kvbi][r] = S[kv0 + truekv][q0+lr], truekv = (kvbi&1)*32+lg*8+(kvbi>>1)*4+r
    float p[16];
#pragma unroll
    for (int kvbi = 0; kvbi < 4; ++kvbi)
#pragma unroll
      for (int r = 0; r < 4; ++r) p[kvbi * 4 + r] = s[kvbi][r];
    if (it == nt - 1) {          // only diagonal-crossing tile masks
#pragma unroll
      for (int kvbi = 0; kvbi < 4; ++kvbi)
#pragma unroll
        for (int r = 0; r < 4; ++r) {
          const int tkv = ((kvbi & 1) << 5) + lg * 8 + ((kvbi >> 1) << 2) + r;
          if (kv0 + tkv > q0 + lr) p[kvbi * 4 + r] = -1e30f;
        }
    }
    // in-lane max tree via v_max3 (T17)
    const float m0_ = max3(p[0], p[1], p[2]);
    const float m1_ = max3(p[3], p[4], p[5]);
    const float m2_ = max3(p[6], p[7], p[8]);
    const float m3_ = max3(p[9], p[10], p[11]);
    const float m4_ = max3(p[12], p[13], p[14]);
    const float mx = fmaxf(max3(m0_, m1_, m2_), max3(m3_, m4_, p[15]));
    // defer-max (T13): log2-domain THR 11.5 == e-domain 8
    if (__any(mx > m + 11.5f)) {
      float cm = mx;
      cm = fmaxf(cm, __shfl_xor(cm, 16, 64));
      cm = fmaxf(cm, __shfl_xor(cm, 32, 64));
      const float mn = fmaxf(m, cm);
      const float al = ex2(m - mn);
      m = mn;
      l *= al;
#pragma unroll
      for (int d = 0; d < 4; ++d)
#pragma unroll
        for (int r = 0; r < 4; ++r) o[d][r] *= al;
    }
#pragma unroll
    for (int i = 0; i < 16; ++i) p[i] = ex2(p[i] - m);
    {  // in-lane partial sum; cross-lane reduce deferred to epilogue
      float s0 = (p[0] + p[1]) + (p[2] + p[3]);
      float s1 = (p[4] + p[5]) + (p[6] + p[7]);
      float s2 = (p[8] + p[9]) + (p[10] + p[11]);
      float s3 = (p[12] + p[13]) + (p[14] + p[15]);
      l += (s0 + s1) + (s2 + s3);
    }
    // PV B-fragments fully in-lane via packed cvt (pk2, R10-proven):
    // pf0[j]=P[lg*8+j], pf1[j]=P[32+lg*8+j]
    BU pf0, pf1;
    pf0.w[0] = pk2(p[0], p[1]);   pf0.w[1] = pk2(p[2], p[3]);
    pf0.w[2] = pk2(p[8], p[9]);   pf0.w[3] = pk2(p[10], p[11]);
    pf1.w[0] = pk2(p[4], p[5]);   pf1.w[1] = pk2(p[6], p[7]);
    pf1.w[2] = pk2(p[12], p[13]); pf1.w[3] = pk2(p[14], p[15]);
    __builtin_amdgcn_s_setprio(1);   // T5 around PV cluster
#pragma unroll
    for (int d = 0; d < 4; ++d) {
      const int row = d * 16 + lr;
      const int sw = (lr & 7) << 4;
      BU v0, v1;
      v0.u = *(const u16x8*)(base + 8192 + row * 128 + ((lg * 16) ^ sw));
      v1.u = *(const u16x8*)(base + 8192 + row * 128 + ((64 + lg * 16) ^ sw));
      o[d] = __builtin_amdgcn_mfma_f32_16x16x32_bf16(v0.b, pf0.b, o[d], 0, 0, 0);
      o[d] = __builtin_amdgcn_mfma_f32_16x16x32_bf16(v1.b, pf1.b, o[d], 0, 0, 0);
    }
    __builtin_amdgcn_s_setprio(0);
    if (more) __syncthreads();   // block-uniform; last iter needs no barrier
    cur ^= 1;
  }

  l += __shfl_xor(l, 16, 64);
  l += __shfl_xor(l, 32, 64);
  const float inv = 1.0f / l;
  const int b = bh >> 4, h = bh & 15;
  const size_t rowo = ((size_t)b * S_ + q0 + lr) * D_ + h * DH_;
#pragma unroll
  for (int d = 0; d < 4; ++d) {
    BU4 w4;
    w4.w[0] = pk2(o[d][0] * inv, o[d][1] * inv);
    w4.w[1] = pk2(o[d][2] * inv, o[d][3] * inv);
    *(u16x4*)(Ao + rowo + d * 16 + lg * 4) = w4.u;
  }
}

// ---------------- launch ----------------
extern "C" void kernel_launch(void* const* d_in, const int* in_sizes, int n_in,
                              void* d_out, int out_size, void* d_ws, size_t ws_size,
                              hipStream_t stream) {
  const float* x = (const float*)d_in[0];
  const float* wqkv = (const float*)d_in[1];
  const float* wproj = (const float*)d_in[2];
  float* out = (float*)d_out;
  char* ws = (char*)d_ws;

  // workspace layout (~76 MB total)
  u16* xb      = (u16*)(ws + 0);          //  8 MB  x bf16 (4096x1024)
  u16* wqkvT   = (u16*)(ws + 8388608);    //  6 MB  w_qkv^T bf16 (3072x1024)
  u16* wprojT  = (u16*)(ws + 14680064);   //  2 MB  w_proj^T bf16 (1024x1024)
  u16* qkvb    = (u16*)(ws + 16777216);   // 24 MB  qkv bf16 (4096x3072)
  u16* Qb      = (u16*)(ws + 41943040);   //  8 MB  [bh][s][dh], pre-scaled
  u16* Kb      = (u16*)(ws + 50331648);   //  8 MB  [bh][s][dh]
  u16* Vtb     = (u16*)(ws + 58720256);   //  8 MB  [bh][dh][s]
  u16* aob     = (u16*)(ws + 67108864);   //  8 MB  attn out (4096x1024)
  float* ct    = (float*)(ws + 75497472); // 256 KB cos table (S x 32)
  float* stab  = (float*)(ws + 75759616); // 256 KB sin table

  k_pre<<<8448, 256, 0, stream>>>(x, wqkv, wproj, xb, wqkvT, wprojT, ct, stab);
  k_gemm<u16><<<768, 256, 0, stream>>>(xb, wqkvT, qkvb, BS_, N3_, D_, 24);
  k_prep<<<1024, 256, 0, stream>>>(qkvb, ct, stab, Qb, Kb, Vtb);
  k_attn<<<1024, 256, 0, stream>>>(Qb, Kb, Vtb, aob);
  k_gemm<float><<<256, 256, 0, stream>>>(aob, wprojT, out, BS_, D_, D_, 8);
}